// Round 4
// baseline (445.740 us; speedup 1.0000x reference)
//
#include <hip/hip_runtime.h>
#include <hip/hip_bf16.h>

// MultiHeadAttention fwd: B=2 S=2048 D=2048 H=16 DH=128, causal, fp32 in/out.
// R4 = R3 resubmit (R3 bench was GPUAcquisitionTimeout; no data).
// R3: QKV GEMM -> 256^2 8-phase template (T3+T4 counted vmcnt, T2 swizzle,
//     T5 setprio, T1 XCD swizzle); 5 cast kernels merged into 1.
// Workspace layout (bytes), total 117,440,512:
//   WQKV 0        : 3*D*D*2 = 25165824   (wq;wk;wv rows, bf16)
//   WO   25165824 : D*D*2   = 8388608
//   XB   33554432 : M*D*2   = 16777216   (x bf16; ALIASED later by attn-out)
//   Qb   50331648 : 16777216             ([B,H,S,DH] bf16, pre-scaled 1/sqrt(DH))
//   Kb   67108864 : 16777216
//   Vb   83886080 : 16777216
//   VT  100663296 : 16777216             ([B,H,DH,S] bf16)

using u16 = unsigned short;
typedef float  f32x4  __attribute__((ext_vector_type(4)));
typedef short  short8 __attribute__((ext_vector_type(8)));

#define DEV __device__ __forceinline__

constexpr int Bc = 2, Sc = 2048, Dc = 2048, Hc = 16, DHc = 128, Mc = 4096, Kc = 2048;
constexpr float RSCALE = 0.08838834764831845f;   // 1/sqrt(128)
constexpr float L2E    = 1.44269504088896341f;

DEV u16 f2bf(float f) { __bf16 h = (__bf16)f; return __builtin_bit_cast(u16, h); }

DEV void gload_lds16(const void* gsrc, void* lds) {
  __builtin_amdgcn_global_load_lds(
      (const __attribute__((address_space(1))) unsigned int*)gsrc,
      (__attribute__((address_space(3))) unsigned int*)lds, 16, 0, 0);
}

// ---------------- fp32 -> bf16 cast, all 5 tensors in one launch ----------
__global__ void cast_all(const float* __restrict__ x, const float* __restrict__ wq,
                         const float* __restrict__ wk, const float* __restrict__ wv,
                         const float* __restrict__ wo, u16* __restrict__ XB,
                         u16* __restrict__ WQKV, u16* __restrict__ WOb) {
  const int i = blockIdx.x * blockDim.x + threadIdx.x;   // float4 index, 6291456 total
  const float4* src;
  u16* dst;
  if (i < 2097152)      { src = (const float4*)x  + i;             dst = XB   + (size_t)i * 4; }
  else if (i < 3145728) { src = (const float4*)wq + (i - 2097152); dst = WQKV + (size_t)(i - 2097152) * 4; }
  else if (i < 4194304) { src = (const float4*)wk + (i - 3145728); dst = WQKV + 4194304 + (size_t)(i - 3145728) * 4; }
  else if (i < 5242880) { src = (const float4*)wv + (i - 4194304); dst = WQKV + 8388608 + (size_t)(i - 4194304) * 4; }
  else                  { src = (const float4*)wo + (i - 5242880); dst = WOb  + (size_t)(i - 5242880) * 4; }
  float4 v = *src;
  u16 o0 = f2bf(v.x), o1 = f2bf(v.y), o2 = f2bf(v.z), o3 = f2bf(v.w);
  dst[0] = o0; dst[1] = o1; dst[2] = o2; dst[3] = o3;
}

// ---------------- QKV GEMM: 256x256 tile, BK=64, 8-phase counted-vmcnt ------
// C[m,n] = sum_k A[m,k]*W[n,k]; A=[4096,2048], W=[6144,2048] (wq;wk;wv).
// 8 waves 2Mx4N, per-wave C = 128x64 (8 M_rep x 4 N_rep). 4 phases per K-tile,
// phase (mq,nq) = 16 MFMA. LDS 128KB: A[2][256][64] natural rows; B[2][256][64]
// with PERMUTED rows r' = ((n>>5)&1)*128 + (n>>6)*32 + (n&31) so each staged
// 64-row chunk == one phase-consumption region. Chunk-XOR swizzle (pc=lc^(row&7))
// applied on the GLOBAL source at stage and on the ds_read address (rule #21).
//
// Stage schedule (iter u computes tile u from dbuf[u&1]=c):
//   ph0: issue (u+1).A.q1 -> dbuf[c^1]   (region last read iter u-1 ph2)
//   ph1: issue (u+1).B.q1 -> dbuf[c^1]   (last read iter u-1 ph1)
//   ph2: issue (u+2).A.q0 -> dbuf[c]     (last read THIS iter ph0, barrier passed)
//   ph3: issue (u+2).B.q0 -> dbuf[c]     (last read THIS iter ph0)
// Every overwrite-issue is >=1 full barrier after the region's last ds_read
// completed (reads drained by the phase's lgkmcnt(0) before that wave's
// barrier-2). vmcnt(4) once per iter: oldest 8 of 12 outstanding = tile u+1
// complete; (u+2).q0 halves may stay in flight across the barrier.
__global__ __launch_bounds__(512, 2) void gemm8p_qkv(
    const u16* __restrict__ A, const u16* __restrict__ W,
    const float* __restrict__ bq, const float* __restrict__ bk,
    const float* __restrict__ bv,
    u16* __restrict__ q_out, u16* __restrict__ k_out, u16* __restrict__ v_out) {
  __shared__ u16 lsA[2][256 * 64];
  __shared__ u16 lsB[2][256 * 64];
  const int tid = threadIdx.x;
  const int lane = tid & 63;
  const int w = tid >> 6;
  const int wr = w >> 2, wc = w & 3;
  const int l15 = lane & 15, l4 = lane >> 4;

  // T1: XCD swizzle, 384 wgs = 48/XCD, grouped by N-panel (bx) for W reuse in L2
  const int id = blockIdx.x;
  const int wg = (id & 7) * 48 + (id >> 3);
  const int bx = wg >> 4;          // N block: 0..23
  const int by = wg & 15;          // M block: 0..15
  const int m0 = by * 256, n0 = bx * 256;

  constexpr int NT = Kc / 64;      // 32 K-tiles

  // staging constants (per-thread)
  const int srow = tid >> 3;       // 0..63: row within the 64-row chunk
  const int spc = tid & 7;         // physical 16B chunk within 128B row
  const int slc = spc ^ (srow & 7);// logical chunk (source pre-swizzle)

  auto stA = [&](int buf, int t, int mq, int h) {
    const int r = h * 128 + mq * 64 + srow;
    gload_lds16(A + (size_t)(m0 + r) * Kc + t * 64 + slc * 8,
                &lsA[buf][(h * 128 + mq * 64) * 64 + tid * 8]);
  };
  auto stB = [&](int buf, int t, int nq, int j) {
    const int rr = j * 64 + srow;                        // 0..127 in nq-half
    const int n = nq * 32 + (rr >> 5) * 64 + (rr & 31);  // inverse row permute
    gload_lds16(W + (size_t)(n0 + n) * Kc + t * 64 + slc * 8,
                &lsB[buf][(nq * 128 + j * 64) * 64 + tid * 8]);
  };

  // ds_read constants
  const int pc0 = l4 ^ (l15 & 7);          // ks=0 swizzled chunk
  const int pc1 = (4 + l4) ^ (l15 & 7);    // ks=1
  const int rA = wr * 128 + l15;           // + mq*64 + fm*16
  const int rB = wc * 32 + l15;            // permuted: + nq*128 + fr*16

  f32x4 acc[8][4] = {};
  short8 af[8], b0[4], b1[4];

  auto ldA = [&](int buf, int mq) {
#pragma unroll
    for (int fm = 0; fm < 4; ++fm) {
      const u16* base = &lsA[buf][(rA + mq * 64 + fm * 16) * 64];
      af[fm * 2 + 0] = *(const short8*)(base + pc0 * 8);
      af[fm * 2 + 1] = *(const short8*)(base + pc1 * 8);
    }
  };
  auto ldB = [&](int buf, int nq, short8* bf) {
#pragma unroll
    for (int fr = 0; fr < 2; ++fr) {
      const u16* base = &lsB[buf][(nq * 128 + rB + fr * 16) * 64];
      bf[fr * 2 + 0] = *(const short8*)(base + pc0 * 8);
      bf[fr * 2 + 1] = *(const short8*)(base + pc1 * 8);
    }
  };
  auto mma = [&](const short8* bf, int mo, int no) {
#pragma unroll
    for (int ks = 0; ks < 2; ++ks)
#pragma unroll
      for (int fm = 0; fm < 4; ++fm)
#pragma unroll
        for (int fr = 0; fr < 2; ++fr)
          acc[mo + fm][no + fr] = __builtin_amdgcn_mfma_f32_16x16x32_bf16(
              af[fm * 2 + ks], bf[fr * 2 + ks], acc[mo + fm][no + fr], 0, 0, 0);
  };

  // prologue: tile0 full (8 insts) + tile1 q0-quarters (4 insts)
  stA(0, 0, 0, 0); stA(0, 0, 0, 1); stA(0, 0, 1, 0); stA(0, 0, 1, 1);
  stB(0, 0, 0, 0); stB(0, 0, 0, 1); stB(0, 0, 1, 0); stB(0, 0, 1, 1);
  stA(1, 1, 0, 0); stA(1, 1, 0, 1); stB(1, 1, 0, 0); stB(1, 1, 0, 1);
  asm volatile("s_waitcnt vmcnt(4)" ::: "memory");   // tile0 landed
  __builtin_amdgcn_s_barrier();

#pragma unroll 1
  for (int u = 0; u < NT; ++u) {
    const int c = u & 1;
    // ---- phase 0 (mq=0, nq=0): 12 ds_read
    ldA(c, 0); ldB(c, 0, b0);
    if (u + 1 < NT) { stA(c ^ 1, u + 1, 1, 0); stA(c ^ 1, u + 1, 1, 1); }
    __builtin_amdgcn_s_barrier();
    asm volatile("s_waitcnt lgkmcnt(0)" ::: "memory");
    __builtin_amdgcn_s_setprio(1); mma(b0, 0, 0); __builtin_amdgcn_s_setprio(0);
    __builtin_amdgcn_s_barrier();
    // ---- phase 1 (mq=0, nq=1): 4 ds_read (af reused)
    ldB(c, 1, b1);
    if (u + 1 < NT) { stB(c ^ 1, u + 1, 1, 0); stB(c ^ 1, u + 1, 1, 1); }
    __builtin_amdgcn_s_barrier();
    asm volatile("s_waitcnt lgkmcnt(0)" ::: "memory");
    __builtin_amdgcn_s_setprio(1); mma(b1, 0, 2); __builtin_amdgcn_s_setprio(0);
    __builtin_amdgcn_s_barrier();
    // ---- phase 2 (mq=1, nq=0): 8 ds_read (b0 reused)
    ldA(c, 1);
    if (u + 2 < NT) { stA(c, u + 2, 0, 0); stA(c, u + 2, 0, 1); }
    __builtin_amdgcn_s_barrier();
    asm volatile("s_waitcnt lgkmcnt(0)" ::: "memory");
    __builtin_amdgcn_s_setprio(1); mma(b0, 4, 0); __builtin_amdgcn_s_setprio(0);
    __builtin_amdgcn_s_barrier();
    // ---- phase 3 (mq=1, nq=1): 0 ds_read (af, b1 reused)
    if (u + 2 < NT) { stB(c, u + 2, 0, 0); stB(c, u + 2, 0, 1); }
    __builtin_amdgcn_s_barrier();
    __builtin_amdgcn_s_setprio(1); mma(b1, 4, 2); __builtin_amdgcn_s_setprio(0);
    if (u + 2 < NT)      asm volatile("s_waitcnt vmcnt(4)" ::: "memory");
    else if (u + 1 < NT) asm volatile("s_waitcnt vmcnt(0)" ::: "memory");
    __builtin_amdgcn_s_barrier();
  }

  // epilogue: QKV scatter + bias (+1/sqrt(DH) folded into Q). Section uniform
  // per block (2048/256=8 blocks per section).
  const int sec = n0 >> 11;
  const int n0s = n0 & 2047;
  const float* bias = sec == 0 ? bq : (sec == 1 ? bk : bv);
  u16* dst = sec == 0 ? q_out : (sec == 1 ? k_out : v_out);
  const float scl = sec == 0 ? RSCALE : 1.0f;
#pragma unroll
  for (int fg = 0; fg < 4; ++fg) {
    const int n2 = n0s + wc * 64 + fg * 16 + l15;
    const float bv_ = bias[n2];
    const int h = n2 >> 7, dh = n2 & 127;
#pragma unroll
    for (int fmg = 0; fmg < 8; ++fmg)
#pragma unroll
      for (int r = 0; r < 4; ++r) {
        const int m = m0 + wr * 128 + fmg * 16 + l4 * 4 + r;
        const int bb = m >> 11, s = m & 2047;
        dst[((size_t)(bb * Hc + h) * Sc + s) * DHc + dh] = f2bf((acc[fmg][fg][r] + bv_) * scl);
      }
  }
}

// ---------------- out-proj GEMM (128^2 m97-structure, kept from R2) ---------
__global__ __launch_bounds__(256) void gemm_bt_out(
    const u16* __restrict__ A, const u16* __restrict__ W,
    const float* __restrict__ bias0, float* __restrict__ f_out) {
  __shared__ u16 lsA[2][128 * 32];
  __shared__ u16 lsB[2][128 * 32];
  const int tid = threadIdx.x;
  const int lane = tid & 63;
  const int w = tid >> 6;
  const int wr = w >> 1, wc = w & 1;
  const int l15 = lane & 15, l4 = lane >> 4;
  const int m0 = blockIdx.y * 128;
  const int n0 = blockIdx.x * 128;

  f32x4 acc[4][4] = {};

  auto stage = [&](int buf, int t) {
    const int k0 = t * 32;
#pragma unroll
    for (int c = 0; c < 2; ++c) {
      int p = c * 256 + tid;
      int row = p >> 2;
      int lg = (p & 3) ^ (row & 3);
      gload_lds16(A + (size_t)(m0 + row) * Kc + k0 + lg * 8, &lsA[buf][p * 8]);
    }
#pragma unroll
    for (int c = 0; c < 2; ++c) {
      int p = c * 256 + tid;
      int row = p >> 2;
      int lg = (p & 3) ^ (row & 3);
      gload_lds16(W + (size_t)(n0 + row) * Kc + k0 + lg * 8, &lsB[buf][p * 8]);
    }
  };

  auto compute = [&](int buf) {
    short8 af[4], bf[4];
#pragma unroll
    for (int mf = 0; mf < 4; ++mf) {
      int row = wr * 64 + mf * 16 + l15;
      int pc = l4 ^ (row & 3);
      af[mf] = *(const short8*)&lsA[buf][row * 32 + pc * 8];
    }
#pragma unroll
    for (int nf = 0; nf < 4; ++nf) {
      int row = wc * 64 + nf * 16 + l15;
      int pc = l4 ^ (row & 3);
      bf[nf] = *(const short8*)&lsB[buf][row * 32 + pc * 8];
    }
#pragma unroll
    for (int mf = 0; mf < 4; ++mf)
#pragma unroll
      for (int nf = 0; nf < 4; ++nf)
        acc[mf][nf] = __builtin_amdgcn_mfma_f32_16x16x32_bf16(af[mf], bf[nf], acc[mf][nf], 0, 0, 0);
  };

  stage(0, 0);
  __syncthreads();
  int buf = 0;
  const int NT = Kc / 32;
  for (int t = 0; t < NT - 1; ++t) {
    stage(buf ^ 1, t + 1);
    compute(buf);
    __syncthreads();
    buf ^= 1;
  }
  compute(buf);

#pragma unroll
  for (int nf = 0; nf < 4; ++nf) {
    const int n = n0 + wc * 64 + nf * 16 + l15;
    const float bias = bias0[n];
#pragma unroll
    for (int mf = 0; mf < 4; ++mf)
#pragma unroll
      for (int r = 0; r < 4; ++r) {
        const int m = m0 + wr * 64 + mf * 16 + l4 * 4 + r;
        f_out[(size_t)m * Dc + n] = acc[mf][nf][r] + bias;
      }
  }
}

// ---------------- V transpose: [B,H,S,DH] -> [B,H,DH,S] ----------------
__global__ void transpose_v(const u16* __restrict__ V, u16* __restrict__ VT) {
  __shared__ u16 t[32][33];
  const int bh = blockIdx.z;
  const int s0 = blockIdx.x * 32;
  const int d0 = blockIdx.y * 32;
  const int tx = threadIdx.x, ty = threadIdx.y;   // 32 x 8
#pragma unroll
  for (int k = 0; k < 4; ++k)
    t[ty + 8 * k][tx] = V[((size_t)bh * Sc + s0 + ty + 8 * k) * DHc + d0 + tx];
  __syncthreads();
#pragma unroll
  for (int k = 0; k < 4; ++k)
    VT[((size_t)bh * DHc + d0 + ty + 8 * k) * Sc + s0 + tx] = t[tx][ty + 8 * k];
}

// ---------------- flash attention (causal), R2 structure ----------------
__global__ __launch_bounds__(256) void fattn(
    const u16* __restrict__ Qb, const u16* __restrict__ Kb,
    const u16* __restrict__ VTb, u16* __restrict__ AO) {
  __shared__ u16 lsK[2][64 * 128];
  __shared__ u16 lsV[2][128 * 64];
  __shared__ u16 lsP[4][16 * 64];

  const int tid = threadIdx.x;
  const int lane = tid & 63;
  const int w = tid >> 6;
  const int l15 = lane & 15, l4 = lane >> 4;

  const int id = blockIdx.x;
  const int xcd = id & 7, seq = id >> 3;     // seq 0..63
  const int bh = xcd + 8 * (seq >> 4);       // 4 bh per XCD
  const int pair = seq & 15;

  const int b = bh >> 4, h = bh & 15;
  const size_t kbase = (size_t)bh * Sc * DHc;
  const size_t vbase = (size_t)bh * DHc * Sc;

#pragma unroll 1
  for (int qsel = 0; qsel < 2; ++qsel) {
    const int qt = qsel ? (31 - pair) : pair;
    const int q0 = qt * 64;
    const int ntiles = qt + 1;

    const size_t qbase = ((size_t)bh * Sc + q0 + w * 16 + l15) * DHc;
    short8 qf[4];
#pragma unroll
    for (int ks = 0; ks < 4; ++ks)
      qf[ks] = *(const short8*)&Qb[qbase + ks * 32 + l4 * 8];

    float m_run[4], l_run[4];
#pragma unroll
    for (int r = 0; r < 4; ++r) { m_run[r] = -__builtin_inff(); l_run[r] = 0.f; }
    f32x4 o_acc[8] = {};

    auto stageKV = [&](int sb, int ti) {
      const int kv0 = ti * 64;
#pragma unroll
      for (int c = 0; c < 4; ++c) {
        int p = c * 256 + tid;
        int row = p >> 4, ph = p & 15;
        int lg = (ph & 8) | ((ph ^ row) & 7);
        gload_lds16(Kb + kbase + (size_t)(kv0 + row) * DHc + lg * 8, &lsK[sb][p * 8]);
      }
#pragma unroll
      for (int c = 0; c < 4; ++c) {
        int p = c * 256 + tid;
        int row = p >> 3, ph = p & 7;
        int lg = ph ^ (row & 7);
        gload_lds16(VTb + vbase + (size_t)row * Sc + kv0 + lg * 8, &lsV[sb][p * 8]);
      }
    };

    stageKV(0, 0);
    asm volatile("s_waitcnt vmcnt(0)" ::: "memory");
    __syncthreads();

    int buf = 0;
#pragma unroll 1
    for (int ti = 0; ti < ntiles; ++ti) {
      const int kv0 = ti * 64;
      if (ti + 1 < ntiles) stageKV(buf ^ 1, ti + 1);

      f32x4 s[4] = {};
      __builtin_amdgcn_s_setprio(1);
#pragma unroll
      for (int nf = 0; nf < 4; ++nf) {
        int row = nf * 16 + l15;
#pragma unroll
        for (int ks = 0; ks < 4; ++ks) {
          int lg = ks * 4 + l4;
          int pc = (lg & 8) | ((lg ^ row) & 7);
          short8 kf = *(const short8*)&lsK[buf][row * 128 + pc * 8];
          s[nf] = __builtin_amdgcn_mfma_f32_16x16x32_bf16(qf[ks], kf, s[nf], 0, 0, 0);
        }
      }
      __builtin_amdgcn_s_setprio(0);

      if (kv0 == q0) {
#pragma unroll
        for (int nf = 0; nf < 4; ++nf) {
          int kc = nf * 16 + l15;
#pragma unroll
          for (int r = 0; r < 4; ++r)
            if (kc > w * 16 + l4 * 4 + r) s[nf][r] = -__builtin_inff();
        }
      }
      float alpha[4];
#pragma unroll
      for (int r = 0; r < 4; ++r) {
        float mx = fmaxf(fmaxf(s[0][r], s[1][r]), fmaxf(s[2][r], s[3][r]));
        mx = fmaxf(mx, __shfl_xor(mx, 1));
        mx = fmaxf(mx, __shfl_xor(mx, 2));
        mx = fmaxf(mx, __shfl_xor(mx, 4));
        mx = fmaxf(mx, __shfl_xor(mx, 8));
        float mnew = fmaxf(m_run[r], mx);
        alpha[r] = __builtin_amdgcn_exp2f((m_run[r] - mnew) * L2E);
        m_run[r] = mnew;
      }
#pragma unroll
      for (int nf = 0; nf < 4; ++nf)
#pragma unroll
        for (int r = 0; r < 4; ++r)
          s[nf][r] = __builtin_amdgcn_exp2f((s[nf][r] - m_run[r]) * L2E);
#pragma unroll
      for (int r = 0; r < 4; ++r) {
        float sm = s[0][r] + s[1][r] + s[2][r] + s[3][r];
        sm += __shfl_xor(sm, 1);
        sm += __shfl_xor(sm, 2);
        sm += __shfl_xor(sm, 4);
        sm += __shfl_xor(sm, 8);
        l_run[r] = l_run[r] * alpha[r] + sm;
      }
#pragma unroll
      for (int nf2 = 0; nf2 < 8; ++nf2)
#pragma unroll
        for (int r = 0; r < 4; ++r) o_acc[nf2][r] *= alpha[r];

#pragma unroll
      for (int nf = 0; nf < 4; ++nf)
#pragma unroll
        for (int r = 0; r < 4; ++r) {
          int rif = l4 * 4 + r;
          int kc = nf * 16 + l15;
          int pc = (kc >> 3) ^ (rif & 7);
          lsP[w][rif * 64 + pc * 8 + (kc & 7)] = f2bf(s[nf][r]);
        }
      asm volatile("s_waitcnt lgkmcnt(0)" ::: "memory");

      __builtin_amdgcn_s_setprio(1);
#pragma unroll
      for (int ks = 0; ks < 2; ++ks) {
        int pc = (ks * 4 + l4) ^ (l15 & 7);
        short8 pa = *(const short8*)&lsP[w][l15 * 64 + pc * 8];
#pragma unroll
        for (int nf2 = 0; nf2 < 8; ++nf2) {
          int vrow = nf2 * 16 + l15;
          int vpc = (ks * 4 + l4) ^ (vrow & 7);
          short8 vb = *(const short8*)&lsV[buf][vrow * 64 + vpc * 8];
          o_acc[nf2] = __builtin_amdgcn_mfma_f32_16x16x32_bf16(pa, vb, o_acc[nf2], 0, 0, 0);
        }
      }
      __builtin_amdgcn_s_setprio(0);

      asm volatile("s_waitcnt vmcnt(0)" ::: "memory");
      __syncthreads();
      buf ^= 1;
    }

#pragma unroll
    for (int nf2 = 0; nf2 < 8; ++nf2)
#pragma unroll
      for (int r = 0; r < 4; ++r) {
        int qr = q0 + w * 16 + l4 * 4 + r;
        float ov = o_acc[nf2][r] / l_run[r];
        AO[((size_t)(b * Sc + qr)) * Dc + h * DHc + nf2 * 16 + l15] = f2bf(ov);
      }
    __syncthreads();
  }
}

// ---------------- launch ----------------
extern "C" void kernel_launch(void* const* d_in, const int* in_sizes, int n_in,
                              void* d_out, int out_size, void* d_ws, size_t ws_size,
                              hipStream_t stream) {
  const float* x  = (const float*)d_in[0];
  // d_in[1] = mask (bool) — causal, known statically; unused
  const float* wq = (const float*)d_in[2];
  const float* bq = (const float*)d_in[3];
  const float* wk = (const float*)d_in[4];
  const float* bk = (const float*)d_in[5];
  const float* wv = (const float*)d_in[6];
  const float* bv = (const float*)d_in[7];
  const float* wo = (const float*)d_in[8];
  const float* bo = (const float*)d_in[9];
  float* out = (float*)d_out;

  char* ws = (char*)d_ws;
  u16* WQKV = (u16*)(ws + 0);
  u16* WOb  = (u16*)(ws + 25165824);
  u16* XB   = (u16*)(ws + 33554432);
  u16* Qb   = (u16*)(ws + 50331648);
  u16* Kb   = (u16*)(ws + 67108864);
  u16* Vb   = (u16*)(ws + 83886080);
  u16* VTb  = (u16*)(ws + 100663296);
  u16* AO   = XB;   // x_bf16 dead after QKV gemm; reuse for attention output

  cast_all<<<dim3(24576), dim3(256), 0, stream>>>(x, wq, wk, wv, wo, XB, WQKV, WOb);
  gemm8p_qkv<<<dim3(384), dim3(512), 0, stream>>>(XB, WQKV, bq, bk, bv, Qb, Kb, Vb);
  transpose_v<<<dim3(64, 4, 32), dim3(32, 8), 0, stream>>>(Vb, VTb);
  fattn<<<dim3(512), dim3(256), 0, stream>>>(Qb, Kb, VTb, AO);
  gemm_bt_out<<<dim3(16, 32), dim3(256), 0, stream>>>(AO, WOb, bo, out);
}

// Round 5
// 425.505 us; speedup vs baseline: 1.0476x; 1.0476x over previous
//
#include <hip/hip_runtime.h>
#include <hip/hip_bf16.h>

// MultiHeadAttention fwd: B=2 S=2048 D=2048 H=16 DH=128, causal, fp32 in/out.
// R5: fix GEMM wave-quantization (R4: 384 blocks / 256 CU = 0.75 util cap).
//   gemm2p<BM,BN,...>: 8 waves (WMxWN, wave-tile 64x64), BK=64, 2 phases/K-tile
//   (16 MFMA each), counted vmcnt(6), both-sides XOR swizzle (R4: conflicts=0),
//   setprio. QKV = <128,256> grid 768 = 3.0/CU; out-proj = <256,128> grid 256
//   = 1.0/CU. fattn/cast/transpose unchanged from R4.
// Workspace layout (bytes), total 117,440,512:
//   WQKV 0        : 3*D*D*2 = 25165824   (wq;wk;wv rows, bf16)
//   WO   25165824 : D*D*2   = 8388608
//   XB   33554432 : M*D*2   = 16777216   (x bf16; ALIASED later by attn-out)
//   Qb   50331648 : 16777216             ([B,H,S,DH] bf16, pre-scaled 1/sqrt(DH))
//   Kb   67108864 : 16777216
//   Vb   83886080 : 16777216
//   VT  100663296 : 16777216             ([B,H,DH,S] bf16)

using u16 = unsigned short;
typedef float  f32x4  __attribute__((ext_vector_type(4)));
typedef short  short8 __attribute__((ext_vector_type(8)));

#define DEV __device__ __forceinline__

constexpr int Bc = 2, Sc = 2048, Dc = 2048, Hc = 16, DHc = 128, Mc = 4096, Kc = 2048;
constexpr float RSCALE = 0.08838834764831845f;   // 1/sqrt(128)
constexpr float L2E    = 1.44269504088896341f;

DEV u16 f2bf(float f) { __bf16 h = (__bf16)f; return __builtin_bit_cast(u16, h); }

DEV void gload_lds16(const void* gsrc, void* lds) {
  __builtin_amdgcn_global_load_lds(
      (const __attribute__((address_space(1))) unsigned int*)gsrc,
      (__attribute__((address_space(3))) unsigned int*)lds, 16, 0, 0);
}

// ---------------- fp32 -> bf16 cast, all 5 tensors in one launch ----------
__global__ void cast_all(const float* __restrict__ x, const float* __restrict__ wq,
                         const float* __restrict__ wk, const float* __restrict__ wv,
                         const float* __restrict__ wo, u16* __restrict__ XB,
                         u16* __restrict__ WQKV, u16* __restrict__ WOb) {
  const int i = blockIdx.x * blockDim.x + threadIdx.x;   // float4 index, 6291456 total
  const float4* src;
  u16* dst;
  if (i < 2097152)      { src = (const float4*)x  + i;             dst = XB   + (size_t)i * 4; }
  else if (i < 3145728) { src = (const float4*)wq + (i - 2097152); dst = WQKV + (size_t)(i - 2097152) * 4; }
  else if (i < 4194304) { src = (const float4*)wk + (i - 3145728); dst = WQKV + 4194304 + (size_t)(i - 3145728) * 4; }
  else if (i < 5242880) { src = (const float4*)wv + (i - 4194304); dst = WQKV + 8388608 + (size_t)(i - 4194304) * 4; }
  else                  { src = (const float4*)wo + (i - 5242880); dst = WOb  + (size_t)(i - 5242880) * 4; }
  float4 v = *src;
  u16 o0 = f2bf(v.x), o1 = f2bf(v.y), o2 = f2bf(v.z), o3 = f2bf(v.w);
  dst[0] = o0; dst[1] = o1; dst[2] = o2; dst[3] = o3;
}

// ---------------- GEMM template: C[m,n] = sum_k A[m,k]*W[n,k], bf16 ---------
// 512 thr = 8 waves arranged WM x WN, wave-tile 64x64 (M_rep=N_rep=4).
// K-tile 64, double-buffered LDS (96 KB). 2 phases per K-tile:
//   ph0: ds_read A-full(8) + B.nq0(4); MFMA 16 (all fm x fr0,1 x ks0,1)
//   ph1: ds_read B.nq1(4);             MFMA 16 (all fm x fr2,3 x ks0,1)
// B rows stored PERMUTED: r' = nq*NH + wc*32 + f*16 + l so each staged 64-row
// gload (8 KB) == one phase-consumption region. Chunk-XOR swizzle pc=lc^(row&7)
// applied on global source at stage AND on ds_read address (rule #21; R4
// measured 0 bank conflicts with this scheme).
// Stage schedule (iter u computes tile u from buf c=u&1; LA=BM/64, LBH=BN/128):
//   prologue: tile0 full (LA+2*LBH) + tile1 A+B.q0 (LA+LBH); vmcnt(LA+LBH); bar
//   ph0 issues B.q1(u+1) -> buf c^1  (region last read iter u-1 ph1, drained)
//   ph1 issues A(u+2)+B.q0(u+2) -> buf c (regions last read THIS iter ph0)
// Wait accounting (per-wave, uniform issue order; wait precedes barrier so the
// barrier publishes all waves' slices):
//   ph0-end needs B.q1(u) [issued ph0(u-1)]; newer = A+Bq0(u+1) + Bq1(u+1)
//     -> vmcnt(LA+2*LBH)=6, or vmcnt(0) at u=NT-1
//   ph1-end needs A+B.q0(u+1) [issued ph1(u-1)]; newer = Bq1(u+1) + A+Bq0(u+2)
//     -> vmcnt(6); tail u=NT-2 -> vmcnt(LBH); u=NT-1 -> none
// EPI 0: QKV scatter+bias (+RSCALE on Q). EPI 1: fp32 out + bias.
template <int BM, int BN, int WM, int WN, int EPI>
__global__ __launch_bounds__(512, 2) void gemm2p(
    const u16* __restrict__ A, const u16* __restrict__ W,
    const float* __restrict__ bias0, const float* __restrict__ bias1,
    const float* __restrict__ bias2,
    u16* __restrict__ q_out, u16* __restrict__ k_out, u16* __restrict__ v_out,
    float* __restrict__ f_out) {
  constexpr int LA  = BM / 64;    // A gloads per K-tile
  constexpr int LBH = BN / 128;   // B gloads per half
  constexpr int NH  = BN / 2;
  static_assert(LA + 2 * LBH == 6, "vmcnt immediates assume 6");
  constexpr int NWR = (EPI == 0) ? 6144 : 2048;   // W rows
  constexpr int NBX = NWR / BN, NBY = Mc / BM, TOT = NBX * NBY, PX = TOT / 8;
  constexpr int NT = Kc / 64;

  __shared__ u16 lsA[2][BM * 64];
  __shared__ u16 lsB[2][BN * 64];

  const int tid = threadIdx.x;
  const int lane = tid & 63;
  const int w = tid >> 6;
  const int wr = w / WN, wc = w % WN;
  const int l15 = lane & 15, l4 = lane >> 4;

  // T1 XCD swizzle (TOT % 8 == 0 -> bijective); consecutive wg share bx panel
  const int id = blockIdx.x;
  const int wg = (id & 7) * PX + (id >> 3);
  const int bx = wg / NBY, by = wg % NBY;
  const int m0 = by * BM, n0 = bx * BN;

  // staging constants
  const int srow = tid >> 3;          // row within 64-row region
  const int spc = tid & 7;            // phys 16B chunk in 128B row
  const int slc = spc ^ (srow & 7);   // source logical chunk (pre-swizzle)

  auto stA = [&](int buf, int t, int j) {
    gload_lds16(A + (size_t)(m0 + j * 64 + srow) * Kc + t * 64 + slc * 8,
                &lsA[buf][j * 4096 + tid * 8]);
  };
  auto stB = [&](int buf, int t, int nq, int j) {
    const int wp = j * 64 + srow;                       // pos within half
    const int n = (wp >> 5) * 64 + nq * 32 + (wp & 31); // inverse row permute
    gload_lds16(W + (size_t)(n0 + n) * Kc + t * 64 + slc * 8,
                &lsB[buf][(nq * NH + j * 64) * 64 + tid * 8]);
  };

  // ds_read swizzled chunk ids (row & 7 == l15 & 7 for all read rows)
  const int pc0 = l4 ^ (l15 & 7);
  const int pc1 = (4 + l4) ^ (l15 & 7);

  f32x4 acc[4][4] = {};
  short8 af[8], b0[4], b1[4];

  auto ldA = [&](int buf) {
#pragma unroll
    for (int fm = 0; fm < 4; ++fm) {
      const u16* base = &lsA[buf][(wr * 64 + fm * 16 + l15) * 64];
      af[fm * 2 + 0] = *(const short8*)(base + pc0 * 8);
      af[fm * 2 + 1] = *(const short8*)(base + pc1 * 8);
    }
  };
  auto ldB = [&](int buf, int nq, short8* bf) {
#pragma unroll
    for (int f = 0; f < 2; ++f) {
      const u16* base = &lsB[buf][(nq * NH + wc * 32 + f * 16 + l15) * 64];
      bf[f * 2 + 0] = *(const short8*)(base + pc0 * 8);
      bf[f * 2 + 1] = *(const short8*)(base + pc1 * 8);
    }
  };
  auto mma = [&](const short8* bf, int nq) {
#pragma unroll
    for (int ks = 0; ks < 2; ++ks)
#pragma unroll
      for (int fm = 0; fm < 4; ++fm)
#pragma unroll
        for (int f = 0; f < 2; ++f)
          acc[fm][nq * 2 + f] = __builtin_amdgcn_mfma_f32_16x16x32_bf16(
              af[fm * 2 + ks], bf[f * 2 + ks], acc[fm][nq * 2 + f], 0, 0, 0);
  };

  // prologue: tile0 full + tile1 {A, B.q0}
#pragma unroll
  for (int j = 0; j < LA; ++j) stA(0, 0, j);
#pragma unroll
  for (int j = 0; j < LBH; ++j) stB(0, 0, 0, j);
#pragma unroll
  for (int j = 0; j < LBH; ++j) stB(0, 0, 1, j);
#pragma unroll
  for (int j = 0; j < LA; ++j) stA(1, 1, j);
#pragma unroll
  for (int j = 0; j < LBH; ++j) stB(1, 1, 0, j);
  if constexpr (LA + LBH == 4) asm volatile("s_waitcnt vmcnt(4)" ::: "memory");
  else                         asm volatile("s_waitcnt vmcnt(5)" ::: "memory");
  __builtin_amdgcn_s_barrier();

#pragma unroll 1
  for (int u = 0; u < NT; ++u) {
    const int c = u & 1;
    // ---- phase 0 ----
    ldA(c);
    ldB(c, 0, b0);
    if (u + 1 < NT) {
#pragma unroll
      for (int j = 0; j < LBH; ++j) stB(c ^ 1, u + 1, 1, j);
    }
    __builtin_amdgcn_s_barrier();
    asm volatile("s_waitcnt lgkmcnt(0)" ::: "memory");
    __builtin_amdgcn_s_setprio(1); mma(b0, 0); __builtin_amdgcn_s_setprio(0);
    if (u + 1 < NT) asm volatile("s_waitcnt vmcnt(6)" ::: "memory");
    else            asm volatile("s_waitcnt vmcnt(0)" ::: "memory");
    __builtin_amdgcn_s_barrier();
    // ---- phase 1 ----
    ldB(c, 1, b1);
    if (u + 2 < NT) {
#pragma unroll
      for (int j = 0; j < LA; ++j) stA(c, u + 2, j);
#pragma unroll
      for (int j = 0; j < LBH; ++j) stB(c, u + 2, 0, j);
    }
    __builtin_amdgcn_s_barrier();
    asm volatile("s_waitcnt lgkmcnt(0)" ::: "memory");
    __builtin_amdgcn_s_setprio(1); mma(b1, 1); __builtin_amdgcn_s_setprio(0);
    if (u + 2 < NT) {
      asm volatile("s_waitcnt vmcnt(6)" ::: "memory");
    } else if (u + 1 < NT) {
      if constexpr (LBH == 2) asm volatile("s_waitcnt vmcnt(2)" ::: "memory");
      else                    asm volatile("s_waitcnt vmcnt(1)" ::: "memory");
    }
    __builtin_amdgcn_s_barrier();
  }

  // epilogue; C/D frag layout col=lane&15, row=(lane>>4)*4+reg [m89/m91]
  if constexpr (EPI == 0) {
    const int sec = n0 >> 11;        // 0:Q 1:K 2:V, uniform per block
    const int n0s = n0 & 2047;
    const float* bias = sec == 0 ? bias0 : (sec == 1 ? bias1 : bias2);
    u16* dst = sec == 0 ? q_out : (sec == 1 ? k_out : v_out);
    const float scl = sec == 0 ? RSCALE : 1.0f;
#pragma unroll
    for (int nf = 0; nf < 4; ++nf) {
      const int n2 = n0s + wc * 64 + nf * 16 + l15;
      const float bv_ = bias[n2];
      const int h = n2 >> 7, dh = n2 & 127;
#pragma unroll
      for (int fm = 0; fm < 4; ++fm)
#pragma unroll
        for (int r = 0; r < 4; ++r) {
          const int m = m0 + wr * 64 + fm * 16 + l4 * 4 + r;
          const int bb = m >> 11, s = m & 2047;
          dst[((size_t)(bb * Hc + h) * Sc + s) * DHc + dh] =
              f2bf((acc[fm][nf][r] + bv_) * scl);
        }
    }
  } else {
#pragma unroll
    for (int nf = 0; nf < 4; ++nf) {
      const int n = n0 + wc * 64 + nf * 16 + l15;
      const float bv_ = bias0[n];
#pragma unroll
      for (int fm = 0; fm < 4; ++fm)
#pragma unroll
        for (int r = 0; r < 4; ++r) {
          const int m = m0 + wr * 64 + fm * 16 + l4 * 4 + r;
          f_out[(size_t)m * Dc + n] = acc[fm][nf][r] + bv_;
        }
    }
  }
}

// ---------------- V transpose: [B,H,S,DH] -> [B,H,DH,S] ----------------
__global__ void transpose_v(const u16* __restrict__ V, u16* __restrict__ VT) {
  __shared__ u16 t[32][33];
  const int bh = blockIdx.z;
  const int s0 = blockIdx.x * 32;
  const int d0 = blockIdx.y * 32;
  const int tx = threadIdx.x, ty = threadIdx.y;   // 32 x 8
#pragma unroll
  for (int k = 0; k < 4; ++k)
    t[ty + 8 * k][tx] = V[((size_t)bh * Sc + s0 + ty + 8 * k) * DHc + d0 + tx];
  __syncthreads();
#pragma unroll
  for (int k = 0; k < 4; ++k)
    VT[((size_t)bh * DHc + d0 + ty + 8 * k) * Sc + s0 + tx] = t[tx][ty + 8 * k];
}

// ---------------- flash attention (causal), R2 structure ----------------
__global__ __launch_bounds__(256) void fattn(
    const u16* __restrict__ Qb, const u16* __restrict__ Kb,
    const u16* __restrict__ VTb, u16* __restrict__ AO) {
  __shared__ u16 lsK[2][64 * 128];
  __shared__ u16 lsV[2][128 * 64];
  __shared__ u16 lsP[4][16 * 64];

  const int tid = threadIdx.x;
  const int lane = tid & 63;
  const int w = tid >> 6;
  const int l15 = lane & 15, l4 = lane >> 4;

  const int id = blockIdx.x;
  const int xcd = id & 7, seq = id >> 3;     // seq 0..63
  const int bh = xcd + 8 * (seq >> 4);       // 4 bh per XCD
  const int pair = seq & 15;

  const int b = bh >> 4, h = bh & 15;
  const size_t kbase = (size_t)bh * Sc * DHc;
  const size_t vbase = (size_t)bh * DHc * Sc;

#pragma unroll 1
  for (int qsel = 0; qsel < 2; ++qsel) {
    const int qt = qsel ? (31 - pair) : pair;
    const int q0 = qt * 64;
    const int ntiles = qt + 1;

    const size_t qbase = ((size_t)bh * Sc + q0 + w * 16 + l15) * DHc;
    short8 qf[4];
#pragma unroll
    for (int ks = 0; ks < 4; ++ks)
      qf[ks] = *(const short8*)&Qb[qbase + ks * 32 + l4 * 8];

    float m_run[4], l_run[4];
#pragma unroll
    for (int r = 0; r < 4; ++r) { m_run[r] = -__builtin_inff(); l_run[r] = 0.f; }
    f32x4 o_acc[8] = {};

    auto stageKV = [&](int sb, int ti) {
      const int kv0 = ti * 64;
#pragma unroll
      for (int c = 0; c < 4; ++c) {
        int p = c * 256 + tid;
        int row = p >> 4, ph = p & 15;
        int lg = (ph & 8) | ((ph ^ row) & 7);
        gload_lds16(Kb + kbase + (size_t)(kv0 + row) * DHc + lg * 8, &lsK[sb][p * 8]);
      }
#pragma unroll
      for (int c = 0; c < 4; ++c) {
        int p = c * 256 + tid;
        int row = p >> 3, ph = p & 7;
        int lg = ph ^ (row & 7);
        gload_lds16(VTb + vbase + (size_t)row * Sc + kv0 + lg * 8, &lsV[sb][p * 8]);
      }
    };

    stageKV(0, 0);
    asm volatile("s_waitcnt vmcnt(0)" ::: "memory");
    __syncthreads();

    int buf = 0;
#pragma unroll 1
    for (int ti = 0; ti < ntiles; ++ti) {
      const int kv0 = ti * 64;
      if (ti + 1 < ntiles) stageKV(buf ^ 1, ti + 1);

      f32x4 s[4] = {};
      __builtin_amdgcn_s_setprio(1);
#pragma unroll
      for (int nf = 0; nf < 4; ++nf) {
        int row = nf * 16 + l15;
#pragma unroll
        for (int ks = 0; ks < 4; ++ks) {
          int lg = ks * 4 + l4;
          int pc = (lg & 8) | ((lg ^ row) & 7);
          short8 kf = *(const short8*)&lsK[buf][row * 128 + pc * 8];
          s[nf] = __builtin_amdgcn_mfma_f32_16x16x32_bf16(qf[ks], kf, s[nf], 0, 0, 0);
        }
      }
      __builtin_amdgcn_s_setprio(0);

      if (kv0 == q0) {
#pragma unroll
        for (int nf = 0; nf < 4; ++nf) {
          int kc = nf * 16 + l15;
#pragma unroll
          for (int r = 0; r < 4; ++r)
            if (kc > w * 16 + l4 * 4 + r) s[nf][r] = -__builtin_inff();
        }
      }
      float alpha[4];
#pragma unroll
      for (int r = 0; r < 4; ++r) {
        float mx = fmaxf(fmaxf(s[0][r], s[1][r]), fmaxf(s[2][r], s[3][r]));
        mx = fmaxf(mx, __shfl_xor(mx, 1));
        mx = fmaxf(mx, __shfl_xor(mx, 2));
        mx = fmaxf(mx, __shfl_xor(mx, 4));
        mx = fmaxf(mx, __shfl_xor(mx, 8));
        float mnew = fmaxf(m_run[r], mx);
        alpha[r] = __builtin_amdgcn_exp2f((m_run[r] - mnew) * L2E);
        m_run[r] = mnew;
      }
#pragma unroll
      for (int nf = 0; nf < 4; ++nf)
#pragma unroll
        for (int r = 0; r < 4; ++r)
          s[nf][r] = __builtin_amdgcn_exp2f((s[nf][r] - m_run[r]) * L2E);
#pragma unroll
      for (int r = 0; r < 4; ++r) {
        float sm = s[0][r] + s[1][r] + s[2][r] + s[3][r];
        sm += __shfl_xor(sm, 1);
        sm += __shfl_xor(sm, 2);
        sm += __shfl_xor(sm, 4);
        sm += __shfl_xor(sm, 8);
        l_run[r] = l_run[r] * alpha[r] + sm;
      }
#pragma unroll
      for (int nf2 = 0; nf2 < 8; ++nf2)
#pragma unroll
        for (int r = 0; r < 4; ++r) o_acc[nf2][r] *= alpha[r];

#pragma unroll
      for (int nf = 0; nf < 4; ++nf)
#pragma unroll
        for (int r = 0; r < 4; ++r) {
          int rif = l4 * 4 + r;
          int kc = nf * 16 + l15;
          int pc = (kc >> 3) ^ (rif & 7);
          lsP[w][rif * 64 + pc * 8 + (kc & 7)] = f2bf(s[nf][r]);
        }
      asm volatile("s_waitcnt lgkmcnt(0)" ::: "memory");

      __builtin_amdgcn_s_setprio(1);
#pragma unroll
      for (int ks = 0; ks < 2; ++ks) {
        int pc = (ks * 4 + l4) ^ (l15 & 7);
        short8 pa = *(const short8*)&lsP[w][l15 * 64 + pc * 8];
#pragma unroll
        for (int nf2 = 0; nf2 < 8; ++nf2) {
          int vrow = nf2 * 16 + l15;
          int vpc = (ks * 4 + l4) ^ (vrow & 7);
          short8 vb = *(const short8*)&lsV[buf][vrow * 64 + vpc * 8];
          o_acc[nf2] = __builtin_amdgcn_mfma_f32_16x16x32_bf16(pa, vb, o_acc[nf2], 0, 0, 0);
        }
      }
      __builtin_amdgcn_s_setprio(0);

      asm volatile("s_waitcnt vmcnt(0)" ::: "memory");
      __syncthreads();
      buf ^= 1;
    }

#pragma unroll
    for (int nf2 = 0; nf2 < 8; ++nf2)
#pragma unroll
      for (int r = 0; r < 4; ++r) {
        int qr = q0 + w * 16 + l4 * 4 + r;
        float ov = o_acc[nf2][r] / l_run[r];
        AO[((size_t)(b * Sc + qr)) * Dc + h * DHc + nf2 * 16 + l15] = f2bf(ov);
      }
    __syncthreads();
  }
}

// ---------------- launch ----------------
extern "C" void kernel_launch(void* const* d_in, const int* in_sizes, int n_in,
                              void* d_out, int out_size, void* d_ws, size_t ws_size,
                              hipStream_t stream) {
  const float* x  = (const float*)d_in[0];
  // d_in[1] = mask (bool) — causal, known statically; unused
  const float* wq = (const float*)d_in[2];
  const float* bq = (const float*)d_in[3];
  const float* wk = (const float*)d_in[4];
  const float* bk = (const float*)d_in[5];
  const float* wv = (const float*)d_in[6];
  const float* bv = (const float*)d_in[7];
  const float* wo = (const float*)d_in[8];
  const float* bo = (const float*)d_in[9];
  float* out = (float*)d_out;

  char* ws = (char*)d_ws;
  u16* WQKV = (u16*)(ws + 0);
  u16* WOb  = (u16*)(ws + 25165824);
  u16* XB   = (u16*)(ws + 33554432);
  u16* Qb   = (u16*)(ws + 50331648);
  u16* Kb   = (u16*)(ws + 67108864);
  u16* Vb   = (u16*)(ws + 83886080);
  u16* VTb  = (u16*)(ws + 100663296);
  u16* AO   = XB;   // x_bf16 dead after QKV gemm; reuse for attention output

  cast_all<<<dim3(24576), dim3(256), 0, stream>>>(x, wq, wk, wv, wo, XB, WQKV, WOb);
  gemm2p<128, 256, 2, 4, 0><<<dim3(768), dim3(512), 0, stream>>>(
      XB, WQKV, bq, bk, bv, Qb, Kb, Vb, nullptr);
  transpose_v<<<dim3(64, 4, 32), dim3(32, 8), 0, stream>>>(Vb, VTb);
  fattn<<<dim3(512), dim3(256), 0, stream>>>(Qb, Kb, VTb, AO);
  gemm2p<256, 128, 4, 2, 1><<<dim3(256), dim3(512), 0, stream>>>(
      AO, WOb, bo, nullptr, nullptr, nullptr, nullptr, nullptr, out);
}

// Round 6
// 397.141 us; speedup vs baseline: 1.1224x; 1.0714x over previous
//
#include <hip/hip_runtime.h>
#include <hip/hip_bf16.h>

// MultiHeadAttention fwd: B=2 S=2048 D=2048 H=16 DH=128, causal, fp32 in/out.
// R6: GEMMs -> 128-row wave-tiles (amortize ~450cyc/phase fixed overhead over
//     24-MFMA phases; LDS-read time < MFMA time), exact CU quantization
//     (QKV 256x192 grid 512 = 2.0 rounds; OP 256x128 grid 256 = 1.0), V
//     written TRANSPOSED by the QKV epilogue (transpose_v deleted).
// Workspace layout (bytes), total 117,440,512:
//   WQKV 0        : 3*D*D*2 = 25165824   (wq;wk;wv rows, bf16)
//   WO   25165824 : D*D*2   = 8388608
//   XB   33554432 : M*D*2   = 16777216   (x bf16; ALIASED later by attn-out)
//   Qb   50331648 : 16777216             ([B,H,S,DH] bf16, pre-scaled 1/sqrt(DH))
//   Kb   67108864 : 16777216
//   (Vb  83886080 : unused since R6)
//   VT  100663296 : 16777216             ([B,H,DH,S] bf16, written by QKV gemm)

using u16 = unsigned short;
typedef float  f32x4  __attribute__((ext_vector_type(4)));
typedef short  short8 __attribute__((ext_vector_type(8)));

#define DEV __device__ __forceinline__

constexpr int Bc = 2, Sc = 2048, Dc = 2048, Hc = 16, DHc = 128, Mc = 4096, Kc = 2048;
constexpr float RSCALE = 0.08838834764831845f;   // 1/sqrt(128)
constexpr float L2E    = 1.44269504088896341f;

DEV u16 f2bf(float f) { __bf16 h = (__bf16)f; return __builtin_bit_cast(u16, h); }

DEV void gload_lds16(const void* gsrc, void* lds) {
  __builtin_amdgcn_global_load_lds(
      (const __attribute__((address_space(1))) unsigned int*)gsrc,
      (__attribute__((address_space(3))) unsigned int*)lds, 16, 0, 0);
}

// ---------------- fp32 -> bf16 cast, all 5 tensors in one launch ----------
__global__ void cast_all(const float* __restrict__ x, const float* __restrict__ wq,
                         const float* __restrict__ wk, const float* __restrict__ wv,
                         const float* __restrict__ wo, u16* __restrict__ XB,
                         u16* __restrict__ WQKV, u16* __restrict__ WOb) {
  const int i = blockIdx.x * blockDim.x + threadIdx.x;   // float4 index, 6291456 total
  const float4* src;
  u16* dst;
  if (i < 2097152)      { src = (const float4*)x  + i;             dst = XB   + (size_t)i * 4; }
  else if (i < 3145728) { src = (const float4*)wq + (i - 2097152); dst = WQKV + (size_t)(i - 2097152) * 4; }
  else if (i < 4194304) { src = (const float4*)wk + (i - 3145728); dst = WQKV + 4194304 + (size_t)(i - 3145728) * 4; }
  else if (i < 5242880) { src = (const float4*)wv + (i - 4194304); dst = WQKV + 8388608 + (size_t)(i - 4194304) * 4; }
  else                  { src = (const float4*)wo + (i - 5242880); dst = WOb  + (size_t)(i - 5242880) * 4; }
  float4 v = *src;
  u16 o0 = f2bf(v.x), o1 = f2bf(v.y), o2 = f2bf(v.z), o3 = f2bf(v.w);
  dst[0] = o0; dst[1] = o1; dst[2] = o2; dst[3] = o3;
}

// ---------------- GEMM: C[m,n] = sum_k A[m,k]*W[n,k], bf16, BM=256 ----------
// 512 thr = 8 waves (2M x 4N), wave-tile 128 x (16*FR). BK=64, dbuf LDS.
// 2 phases per K-tile, each = one fm-half:
//   ph0: ds_read A-half0 (8) + B-all (2*FR); 4*FR*2 MFMA
//   ph1: ds_read A-half1 (8);                4*FR*2 MFMA  (B frags persist)
// Chunk-XOR swizzle pc = lc ^ (row&7) on global source AND ds_read addr
// (rule #21; R4/R5 measured 0 bank conflicts). All read rows have row&7 ==
// l15&7 (wr*128, half*64, fm*16, wc*16FR all 0 mod 8... wc*48 = 0 mod 16).
// Staging, depth-1 prefetch (regions: B = LB x 64 rows, A = 4 x 64 rows;
// A half0 = regions {0,2}, half1 = {1,3}):
//   ph0(u): issue B(u+1) [LB] + A-h0(u+1) [2] -> buf c^1
//   ph1(u): issue A-h1(u+1) [2]              -> buf c^1
// Legality: each overwritten region's last ds_read drained (lgkmcnt(0)) >= 1
// barrier before the issue. Per-wave vmcnt accounting (issue order B,Ah0,Ah1):
//   end-ph0(u): need Ah1(u) [ph1(u-1)]; newer = ph0(u)'s LB+2 -> vmcnt(LB+2)
//               (tail u=NT-1: nothing newer -> vmcnt(0))
//   end-ph1(u): need B,Ah0(u+1) [ph0(u)]; newer = ph1(u)'s 2 -> vmcnt(2)
// Wait precedes the closing barrier, so barrier publishes all waves' slices.
// EPI 0 (QKV, NWR=6144): per-LANE section resolve (BN=192 doesn't align to
// the 2048 section boundary); Q/K scatter [B,H,S,DH] (+bias, Q*RSCALE);
// V written TRANSPOSED to VT [B,H,DH,S] as packed ushort4 along s.
// EPI 1 (out-proj, NWR=2048): fp32 += bias row-major.
template <int BN, int FR, int EPI>
__global__ __launch_bounds__(512, 2) void gemm2p(
    const u16* __restrict__ A, const u16* __restrict__ W,
    const float* __restrict__ bias0, const float* __restrict__ bias1,
    const float* __restrict__ bias2,
    u16* __restrict__ q_out, u16* __restrict__ k_out, u16* __restrict__ vt_out,
    float* __restrict__ f_out) {
  constexpr int LB = BN / 64;               // B gloads per K-tile
  constexpr int NWR = (EPI == 0) ? 6144 : 2048;
  constexpr int NBX = NWR / BN, NBY = Mc / 256, TOT = NBX * NBY, PX = TOT / 8;
  constexpr int NT = Kc / 64;
  static_assert(BN == FR * 64, "8 waves: 4 N-cols x 16*FR");

  __shared__ u16 lsA[2][256 * 64];
  __shared__ u16 lsB[2][BN * 64];

  const int tid = threadIdx.x;
  const int lane = tid & 63;
  const int w = tid >> 6;
  const int wr = w >> 2, wc = w & 3;
  const int l15 = lane & 15, l4 = lane >> 4;

  // T1 XCD swizzle (TOT % 8 == 0 -> bijective)
  const int id = blockIdx.x;
  const int wg = (id & 7) * PX + (id >> 3);
  const int bx = wg / NBY, by = wg % NBY;
  const int m0 = by * 256, n0 = bx * BN;

  // staging constants
  const int srow = tid >> 3;          // row within 64-row region
  const int spc = tid & 7;            // phys 16B chunk in 128B row
  const int slc = spc ^ (srow & 7);   // source logical chunk (pre-swizzle)

  auto stA = [&](int buf, int t, int j) {   // j = region 0..3 (rows j*64..+63)
    gload_lds16(A + (size_t)(m0 + j * 64 + srow) * Kc + t * 64 + slc * 8,
                &lsA[buf][j * 4096 + tid * 8]);
  };
  auto stB = [&](int buf, int t, int j) {   // j = 0..LB-1
    gload_lds16(W + (size_t)(n0 + j * 64 + srow) * Kc + t * 64 + slc * 8,
                &lsB[buf][j * 4096 + tid * 8]);
  };

  const int pc0 = l4 ^ (l15 & 7);
  const int pc1 = (4 + l4) ^ (l15 & 7);

  f32x4 acc[8][FR] = {};
  short8 af[8], bf[FR * 2];

  auto ldA = [&](int buf, int half) {
#pragma unroll
    for (int fm = 0; fm < 4; ++fm) {
      const u16* base = &lsA[buf][(wr * 128 + half * 64 + fm * 16 + l15) * 64];
      af[fm * 2 + 0] = *(const short8*)(base + pc0 * 8);
      af[fm * 2 + 1] = *(const short8*)(base + pc1 * 8);
    }
  };
  auto ldB = [&](int buf) {
#pragma unroll
    for (int f = 0; f < FR; ++f) {
      const u16* base = &lsB[buf][(wc * (16 * FR) + f * 16 + l15) * 64];
      bf[f * 2 + 0] = *(const short8*)(base + pc0 * 8);
      bf[f * 2 + 1] = *(const short8*)(base + pc1 * 8);
    }
  };
  auto mma = [&](int half) {
#pragma unroll
    for (int ks = 0; ks < 2; ++ks)
#pragma unroll
      for (int fm = 0; fm < 4; ++fm)
#pragma unroll
        for (int f = 0; f < FR; ++f)
          acc[half * 4 + fm][f] = __builtin_amdgcn_mfma_f32_16x16x32_bf16(
              af[fm * 2 + ks], bf[f * 2 + ks], acc[half * 4 + fm][f], 0, 0, 0);
  };

  // prologue: tile0 in order [B, A-h0, A-h1]
#pragma unroll
  for (int j = 0; j < LB; ++j) stB(0, 0, j);
  stA(0, 0, 0); stA(0, 0, 2);
  stA(0, 0, 1); stA(0, 0, 3);
  asm volatile("s_waitcnt vmcnt(2)" ::: "memory");   // B(0), A-h0(0) landed
  __builtin_amdgcn_s_barrier();

#pragma unroll 1
  for (int u = 0; u < NT; ++u) {
    const int c = u & 1;
    // ---- phase 0 (fm half 0) ----
    ldA(c, 0);
    ldB(c);
    if (u + 1 < NT) {
#pragma unroll
      for (int j = 0; j < LB; ++j) stB(c ^ 1, u + 1, j);
      stA(c ^ 1, u + 1, 0); stA(c ^ 1, u + 1, 2);
    }
    __builtin_amdgcn_s_barrier();
    asm volatile("s_waitcnt lgkmcnt(0)" ::: "memory");
    __builtin_amdgcn_s_setprio(1); mma(0); __builtin_amdgcn_s_setprio(0);
    if (u + 1 < NT) {
      if constexpr (LB == 3) asm volatile("s_waitcnt vmcnt(5)" ::: "memory");
      else                   asm volatile("s_waitcnt vmcnt(4)" ::: "memory");
    } else {
      asm volatile("s_waitcnt vmcnt(0)" ::: "memory");
    }
    __builtin_amdgcn_s_barrier();
    // ---- phase 1 (fm half 1) ----
    ldA(c, 1);
    if (u + 1 < NT) { stA(c ^ 1, u + 1, 1); stA(c ^ 1, u + 1, 3); }
    __builtin_amdgcn_s_barrier();
    asm volatile("s_waitcnt lgkmcnt(0)" ::: "memory");
    __builtin_amdgcn_s_setprio(1); mma(1); __builtin_amdgcn_s_setprio(0);
    if (u + 1 < NT) asm volatile("s_waitcnt vmcnt(2)" ::: "memory");
    __builtin_amdgcn_s_barrier();
  }

  // epilogue; C/D frag layout col=lane&15, row=(lane>>4)*4+reg [m89/m91]
  if constexpr (EPI == 0) {
#pragma unroll
    for (int f = 0; f < FR; ++f) {
      const int n = n0 + wc * (16 * FR) + f * 16 + l15;   // per-lane global col
      const int sec = n >> 11;                            // 0:Q 1:K 2:V (per lane!)
      const int n2 = n & 2047;
      const float bias = sec == 0 ? bias0[n2] : (sec == 1 ? bias1[n2] : bias2[n2]);
      const int h = n2 >> 7, dh = n2 & 127;
#pragma unroll
      for (int fm = 0; fm < 8; ++fm) {
        const int m = m0 + wr * 128 + fm * 16 + l4 * 4;   // +r, r=0..3
        const int bb = m >> 11, s = m & 2047;
        if (sec < 2) {
          const float scl = sec == 0 ? RSCALE : 1.0f;
          u16* dst = sec == 0 ? q_out : k_out;
#pragma unroll
          for (int r = 0; r < 4; ++r)
            dst[((size_t)(bb * Hc + h) * Sc + s + r) * DHc + dh] =
                f2bf((acc[fm][f][r] + bias) * scl);
        } else {
          ushort4 pk;
          pk.x = f2bf(acc[fm][f][0] + bias);
          pk.y = f2bf(acc[fm][f][1] + bias);
          pk.z = f2bf(acc[fm][f][2] + bias);
          pk.w = f2bf(acc[fm][f][3] + bias);
          *(ushort4*)&vt_out[((size_t)(bb * Hc + h) * DHc + dh) * Sc + s] = pk;
        }
      }
    }
  } else {
#pragma unroll
    for (int f = 0; f < FR; ++f) {
      const int n = n0 + wc * (16 * FR) + f * 16 + l15;
      const float bias = bias0[n];
#pragma unroll
      for (int fm = 0; fm < 8; ++fm) {
        const int m = m0 + wr * 128 + fm * 16 + l4 * 4;
#pragma unroll
        for (int r = 0; r < 4; ++r)
          f_out[(size_t)(m + r) * Dc + n] = acc[fm][f][r] + bias;
      }
    }
  }
}

// ---------------- flash attention (causal), R2 structure ----------------
__global__ __launch_bounds__(256) void fattn(
    const u16* __restrict__ Qb, const u16* __restrict__ Kb,
    const u16* __restrict__ VTb, u16* __restrict__ AO) {
  __shared__ u16 lsK[2][64 * 128];
  __shared__ u16 lsV[2][128 * 64];
  __shared__ u16 lsP[4][16 * 64];

  const int tid = threadIdx.x;
  const int lane = tid & 63;
  const int w = tid >> 6;
  const int l15 = lane & 15, l4 = lane >> 4;

  const int id = blockIdx.x;
  const int xcd = id & 7, seq = id >> 3;     // seq 0..63
  const int bh = xcd + 8 * (seq >> 4);       // 4 bh per XCD
  const int pair = seq & 15;

  const int b = bh >> 4, h = bh & 15;
  const size_t kbase = (size_t)bh * Sc * DHc;
  const size_t vbase = (size_t)bh * DHc * Sc;

#pragma unroll 1
  for (int qsel = 0; qsel < 2; ++qsel) {
    const int qt = qsel ? (31 - pair) : pair;
    const int q0 = qt * 64;
    const int ntiles = qt + 1;

    const size_t qbase = ((size_t)bh * Sc + q0 + w * 16 + l15) * DHc;
    short8 qf[4];
#pragma unroll
    for (int ks = 0; ks < 4; ++ks)
      qf[ks] = *(const short8*)&Qb[qbase + ks * 32 + l4 * 8];

    float m_run[4], l_run[4];
#pragma unroll
    for (int r = 0; r < 4; ++r) { m_run[r] = -__builtin_inff(); l_run[r] = 0.f; }
    f32x4 o_acc[8] = {};

    auto stageKV = [&](int sb, int ti) {
      const int kv0 = ti * 64;
#pragma unroll
      for (int c = 0; c < 4; ++c) {
        int p = c * 256 + tid;
        int row = p >> 4, ph = p & 15;
        int lg = (ph & 8) | ((ph ^ row) & 7);
        gload_lds16(Kb + kbase + (size_t)(kv0 + row) * DHc + lg * 8, &lsK[sb][p * 8]);
      }
#pragma unroll
      for (int c = 0; c < 4; ++c) {
        int p = c * 256 + tid;
        int row = p >> 3, ph = p & 7;
        int lg = ph ^ (row & 7);
        gload_lds16(VTb + vbase + (size_t)row * Sc + kv0 + lg * 8, &lsV[sb][p * 8]);
      }
    };

    stageKV(0, 0);
    asm volatile("s_waitcnt vmcnt(0)" ::: "memory");
    __syncthreads();

    int buf = 0;
#pragma unroll 1
    for (int ti = 0; ti < ntiles; ++ti) {
      const int kv0 = ti * 64;
      if (ti + 1 < ntiles) stageKV(buf ^ 1, ti + 1);

      f32x4 s[4] = {};
      __builtin_amdgcn_s_setprio(1);
#pragma unroll
      for (int nf = 0; nf < 4; ++nf) {
        int row = nf * 16 + l15;
#pragma unroll
        for (int ks = 0; ks < 4; ++ks) {
          int lg = ks * 4 + l4;
          int pc = (lg & 8) | ((lg ^ row) & 7);
          short8 kf = *(const short8*)&lsK[buf][row * 128 + pc * 8];
          s[nf] = __builtin_amdgcn_mfma_f32_16x16x32_bf16(qf[ks], kf, s[nf], 0, 0, 0);
        }
      }
      __builtin_amdgcn_s_setprio(0);

      if (kv0 == q0) {
#pragma unroll
        for (int nf = 0; nf < 4; ++nf) {
          int kc = nf * 16 + l15;
#pragma unroll
          for (int r = 0; r < 4; ++r)
            if (kc > w * 16 + l4 * 4 + r) s[nf][r] = -__builtin_inff();
        }
      }
      float alpha[4];
#pragma unroll
      for (int r = 0; r < 4; ++r) {
        float mx = fmaxf(fmaxf(s[0][r], s[1][r]), fmaxf(s[2][r], s[3][r]));
        mx = fmaxf(mx, __shfl_xor(mx, 1));
        mx = fmaxf(mx, __shfl_xor(mx, 2));
        mx = fmaxf(mx, __shfl_xor(mx, 4));
        mx = fmaxf(mx, __shfl_xor(mx, 8));
        float mnew = fmaxf(m_run[r], mx);
        alpha[r] = __builtin_amdgcn_exp2f((m_run[r] - mnew) * L2E);
        m_run[r] = mnew;
      }
#pragma unroll
      for (int nf = 0; nf < 4; ++nf)
#pragma unroll
        for (int r = 0; r < 4; ++r)
          s[nf][r] = __builtin_amdgcn_exp2f((s[nf][r] - m_run[r]) * L2E);
#pragma unroll
      for (int r = 0; r < 4; ++r) {
        float sm = s[0][r] + s[1][r] + s[2][r] + s[3][r];
        sm += __shfl_xor(sm, 1);
        sm += __shfl_xor(sm, 2);
        sm += __shfl_xor(sm, 4);
        sm += __shfl_xor(sm, 8);
        l_run[r] = l_run[r] * alpha[r] + sm;
      }
#pragma unroll
      for (int nf2 = 0; nf2 < 8; ++nf2)
#pragma unroll
        for (int r = 0; r < 4; ++r) o_acc[nf2][r] *= alpha[r];

#pragma unroll
      for (int nf = 0; nf < 4; ++nf)
#pragma unroll
        for (int r = 0; r < 4; ++r) {
          int rif = l4 * 4 + r;
          int kc = nf * 16 + l15;
          int pc = (kc >> 3) ^ (rif & 7);
          lsP[w][rif * 64 + pc * 8 + (kc & 7)] = f2bf(s[nf][r]);
        }
      asm volatile("s_waitcnt lgkmcnt(0)" ::: "memory");

      __builtin_amdgcn_s_setprio(1);
#pragma unroll
      for (int ks = 0; ks < 2; ++ks) {
        int pc = (ks * 4 + l4) ^ (l15 & 7);
        short8 pa = *(const short8*)&lsP[w][l15 * 64 + pc * 8];
#pragma unroll
        for (int nf2 = 0; nf2 < 8; ++nf2) {
          int vrow = nf2 * 16 + l15;
          int vpc = (ks * 4 + l4) ^ (vrow & 7);
          short8 vb = *(const short8*)&lsV[buf][vrow * 64 + vpc * 8];
          o_acc[nf2] = __builtin_amdgcn_mfma_f32_16x16x32_bf16(pa, vb, o_acc[nf2], 0, 0, 0);
        }
      }
      __builtin_amdgcn_s_setprio(0);

      asm volatile("s_waitcnt vmcnt(0)" ::: "memory");
      __syncthreads();
      buf ^= 1;
    }

#pragma unroll
    for (int nf2 = 0; nf2 < 8; ++nf2)
#pragma unroll
      for (int r = 0; r < 4; ++r) {
        int qr = q0 + w * 16 + l4 * 4 + r;
        float ov = o_acc[nf2][r] / l_run[r];
        AO[((size_t)(b * Sc + qr)) * Dc + h * DHc + nf2 * 16 + l15] = f2bf(ov);
      }
    __syncthreads();
  }
}

// ---------------- launch ----------------
extern "C" void kernel_launch(void* const* d_in, const int* in_sizes, int n_in,
                              void* d_out, int out_size, void* d_ws, size_t ws_size,
                              hipStream_t stream) {
  const float* x  = (const float*)d_in[0];
  // d_in[1] = mask (bool) — causal, known statically; unused
  const float* wq = (const float*)d_in[2];
  const float* bq = (const float*)d_in[3];
  const float* wk = (const float*)d_in[4];
  const float* bk = (const float*)d_in[5];
  const float* wv = (const float*)d_in[6];
  const float* bv = (const float*)d_in[7];
  const float* wo = (const float*)d_in[8];
  const float* bo = (const float*)d_in[9];
  float* out = (float*)d_out;

  char* ws = (char*)d_ws;
  u16* WQKV = (u16*)(ws + 0);
  u16* WOb  = (u16*)(ws + 25165824);
  u16* XB   = (u16*)(ws + 33554432);
  u16* Qb   = (u16*)(ws + 50331648);
  u16* Kb   = (u16*)(ws + 67108864);
  u16* VTb  = (u16*)(ws + 100663296);
  u16* AO   = XB;   // x_bf16 dead after QKV gemm; reuse for attention output

  cast_all<<<dim3(24576), dim3(256), 0, stream>>>(x, wq, wk, wv, wo, XB, WQKV, WOb);
  gemm2p<192, 3, 0><<<dim3(512), dim3(512), 0, stream>>>(
      XB, WQKV, bq, bk, bv, Qb, Kb, VTb, nullptr);
  fattn<<<dim3(512), dim3(256), 0, stream>>>(Qb, Kb, VTb, AO);
  gemm2p<128, 2, 1><<<dim3(256), dim3(512), 0, stream>>>(
      AO, WOb, bo, nullptr, nullptr, nullptr, nullptr, nullptr, out);
}